// Round 1
// baseline (89.500 us; speedup 1.0000x reference)
//
#include <hip/hip_runtime.h>
#include <hip/hip_bf16.h>

#define N 4096
#define NSTEPS 256

// ---------------------------------------------------------------------------
// Kernel 1: a = U@z + V@x  (complex matvec, fp32)
// One block (256 threads) per output row. Coalesced float4 loads of the four
// matrix rows; the 4 input vectors (4x16KB) stay L1/L2-resident.
// a_re[row] = sum_c Ur*zr - Ui*zi + Vr*xr - Vi*xi
// a_im[row] = sum_c Ur*zi + Ui*zr + Vr*xi + Vi*xr
// ---------------------------------------------------------------------------
__global__ __launch_bounds__(256) void matvec_kernel(
    const float* __restrict__ Ur, const float* __restrict__ Ui,
    const float* __restrict__ Vr, const float* __restrict__ Vi,
    const float* __restrict__ zr, const float* __restrict__ zi,
    const float* __restrict__ xr, const float* __restrict__ xi,
    float* __restrict__ a_re, float* __restrict__ a_im)
{
    const int row = blockIdx.x;
    const size_t base = (size_t)row * N;

    const float4* ur4 = (const float4*)(Ur + base);
    const float4* ui4 = (const float4*)(Ui + base);
    const float4* vr4 = (const float4*)(Vr + base);
    const float4* vi4 = (const float4*)(Vi + base);
    const float4* zr4 = (const float4*)zr;
    const float4* zi4 = (const float4*)zi;
    const float4* xr4 = (const float4*)xr;
    const float4* xi4 = (const float4*)xi;

    float sr = 0.0f, si = 0.0f;

    // N/4 float4 columns = 1024; 256 threads -> 4 iterations
    #pragma unroll
    for (int it = 0; it < N / 4 / 256; ++it) {
        const int c4 = it * 256 + threadIdx.x;
        const float4 ur = ur4[c4];
        const float4 ui = ui4[c4];
        const float4 vr = vr4[c4];
        const float4 vi = vi4[c4];
        const float4 zrv = zr4[c4];
        const float4 ziv = zi4[c4];
        const float4 xrv = xr4[c4];
        const float4 xiv = xi4[c4];

        sr += ur.x * zrv.x - ui.x * ziv.x + vr.x * xrv.x - vi.x * xiv.x;
        si += ur.x * ziv.x + ui.x * zrv.x + vr.x * xiv.x + vi.x * xrv.x;
        sr += ur.y * zrv.y - ui.y * ziv.y + vr.y * xrv.y - vi.y * xiv.y;
        si += ur.y * ziv.y + ui.y * zrv.y + vr.y * xiv.y + vi.y * xrv.y;
        sr += ur.z * zrv.z - ui.z * ziv.z + vr.z * xrv.z - vi.z * xiv.z;
        si += ur.z * ziv.z + ui.z * zrv.z + vr.z * xiv.z + vi.z * xrv.z;
        sr += ur.w * zrv.w - ui.w * ziv.w + vr.w * xrv.w - vi.w * xiv.w;
        si += ur.w * ziv.w + ui.w * zrv.w + vr.w * xiv.w + vi.w * xrv.w;
    }

    // wave (64-lane) shuffle reduction, then cross-wave via LDS
    #pragma unroll
    for (int off = 32; off > 0; off >>= 1) {
        sr += __shfl_down(sr, off);
        si += __shfl_down(si, off);
    }
    __shared__ float lsr[4], lsi[4];
    const int wave = threadIdx.x >> 6;
    const int lane = threadIdx.x & 63;
    if (lane == 0) { lsr[wave] = sr; lsi[wave] = si; }
    __syncthreads();
    if (threadIdx.x == 0) {
        a_re[row] = lsr[0] + lsr[1] + lsr[2] + lsr[3];
        a_im[row] = lsi[0] + lsi[1] + lsi[2] + lsi[3];
    }
}

// ---------------------------------------------------------------------------
// Kernel 2: per-element DOPRI5 fixed-step integration of
//   dz/dt = (a - |z|^2) z   over [0, 2*pi], 256 steps, fp32 (matches ref).
// One thread per element; sequential dependent chain (latency-bound).
// ---------------------------------------------------------------------------
__device__ __forceinline__ void hopf_f(float ar, float ai, float zr, float zi,
                                       float& fr, float& fi)
{
    const float m  = zr * zr + zi * zi;   // conj(z)*z is real
    const float cr = ar - m;              // c = (ar - m) + i*ai
    fr = cr * zr - ai * zi;
    fi = cr * zi + ai * zr;
}

__global__ __launch_bounds__(256) void ode_kernel(
    const float* __restrict__ a_re, const float* __restrict__ a_im,
    const float* __restrict__ z_re, const float* __restrict__ z_im,
    float* __restrict__ out)
{
    const int i = blockIdx.x * blockDim.x + threadIdx.x;
    if (i >= N) return;

    const float ar = a_re[i];
    const float ai = a_im[i];
    float zr = z_re[i];
    float zi = z_im[i];

    const float h = (float)(6.283185307179586 / (double)NSTEPS);

    for (int s = 0; s < NSTEPS; ++s) {
        float k1r, k1i, k2r, k2i, k3r, k3i, k4r, k4i, k5r, k5i, k6r, k6i;

        hopf_f(ar, ai, zr, zi, k1r, k1i);

        hopf_f(ar, ai,
               zr + h * (0.2f * k1r),
               zi + h * (0.2f * k1i), k2r, k2i);

        hopf_f(ar, ai,
               zr + h * ((3.0f/40.0f) * k1r + (9.0f/40.0f) * k2r),
               zi + h * ((3.0f/40.0f) * k1i + (9.0f/40.0f) * k2i), k3r, k3i);

        hopf_f(ar, ai,
               zr + h * ((44.0f/45.0f) * k1r - (56.0f/15.0f) * k2r + (32.0f/9.0f) * k3r),
               zi + h * ((44.0f/45.0f) * k1i - (56.0f/15.0f) * k2i + (32.0f/9.0f) * k3i),
               k4r, k4i);

        hopf_f(ar, ai,
               zr + h * ((19372.0f/6561.0f) * k1r - (25360.0f/2187.0f) * k2r
                         + (64448.0f/6561.0f) * k3r - (212.0f/729.0f) * k4r),
               zi + h * ((19372.0f/6561.0f) * k1i - (25360.0f/2187.0f) * k2i
                         + (64448.0f/6561.0f) * k3i - (212.0f/729.0f) * k4i),
               k5r, k5i);

        hopf_f(ar, ai,
               zr + h * ((9017.0f/3168.0f) * k1r - (355.0f/33.0f) * k2r
                         + (46732.0f/5247.0f) * k3r + (49.0f/176.0f) * k4r
                         - (5103.0f/18656.0f) * k5r),
               zi + h * ((9017.0f/3168.0f) * k1i - (355.0f/33.0f) * k2i
                         + (46732.0f/5247.0f) * k3i + (49.0f/176.0f) * k4i
                         - (5103.0f/18656.0f) * k5i),
               k6r, k6i);

        zr = zr + h * ((35.0f/384.0f) * k1r + (500.0f/1113.0f) * k3r
                       + (125.0f/192.0f) * k4r - (2187.0f/6784.0f) * k5r
                       + (11.0f/84.0f) * k6r);
        zi = zi + h * ((35.0f/384.0f) * k1i + (500.0f/1113.0f) * k3i
                       + (125.0f/192.0f) * k4i - (2187.0f/6784.0f) * k5i
                       + (11.0f/84.0f) * k6i);
    }

    out[i]     = zr;   // real part  -> out[0, :, 0]
    out[N + i] = zi;   // imag part  -> out[1, :, 0]
}

extern "C" void kernel_launch(void* const* d_in, const int* in_sizes, int n_in,
                              void* d_out, int out_size, void* d_ws, size_t ws_size,
                              hipStream_t stream)
{
    const float* x_re = (const float*)d_in[0];
    const float* x_im = (const float*)d_in[1];
    const float* z_re = (const float*)d_in[2];
    const float* z_im = (const float*)d_in[3];
    const float* U_re = (const float*)d_in[4];
    const float* U_im = (const float*)d_in[5];
    const float* V_re = (const float*)d_in[6];
    const float* V_im = (const float*)d_in[7];

    float* out  = (float*)d_out;
    float* a_re = (float*)d_ws;        // N floats
    float* a_im = a_re + N;            // N floats

    matvec_kernel<<<N, 256, 0, stream>>>(U_re, U_im, V_re, V_im,
                                         z_re, z_im, x_re, x_im,
                                         a_re, a_im);

    ode_kernel<<<N / 256, 256, 0, stream>>>(a_re, a_im, z_re, z_im, out);
}